// Round 10
// baseline (121.398 us; speedup 1.0000x reference)
//
#include <hip/hip_runtime.h>
#include <stdint.h>

#define Hh 192
#define Ww 192
#define HW 36864            // 192*192
#define CROPW 38
#define CW2 1444            // 38*38
#define CROPOFF 77
#define NPTS 11552          // 8*38*38
#define NPAD 11776          // 92*128
#define NMT 92              // 128-row tiles
#define NCT 92              // 128-col tiles
#define NG 5                // col-tile groups
#define JPB 19              // col-tiles per group (last group gets 16)
#define NBLK (NG*NMT)       // 460 blocks
#define SLABB 512           // 8 b * 64 channel-pairs
#define CROPB 304           // 38*8 crop blocks
#define BIGF 3.0e38f

typedef short bf16x8 __attribute__((ext_vector_type(8)));
typedef float f32x4 __attribute__((ext_vector_type(4)));
typedef float f32x16 __attribute__((ext_vector_type(16)));
typedef uint32_t u32x4 __attribute__((ext_vector_type(4)));
typedef unsigned short ushort;

__device__ __forceinline__ ushort f2bf(float f) {
  uint32_t b = __float_as_uint(f);
  uint32_t r = b + 0x7fffu + ((b >> 16) & 1u);
  return (ushort)(r >> 16);
}
__device__ __forceinline__ float bf2f(ushort u) {
  return __uint_as_float(((uint32_t)u) << 16);
}

__device__ __forceinline__ void g2l16(const void* g, void* l) {
  __builtin_amdgcn_global_load_lds(
      (const __attribute__((address_space(1))) unsigned int*)g,
      (__attribute__((address_space(3))) unsigned int*)l, 16, 0, 0);
}

// ---- fused sampler: slab blocks (feat2->pB,d2) + crop blocks (feat1->aB,d1) ----
__global__ __launch_bounds__(1024) void fused_k(
    const float* __restrict__ feat1, const float* __restrict__ feat2,
    const float* __restrict__ aflow,
    ushort* __restrict__ aB, ushort* __restrict__ pB,
    float* __restrict__ d1, float* __restrict__ d2) {
  __shared__ __align__(16) uint32_t plane[HW];   // 144 KB (slab) / reused by crop
  int bid = blockIdx.x;
  int t = threadIdx.x;

  if (bid < SLABB) {
    // ---------------- slab: (b, channel-pair) ----------------
    int b = bid >> 6, c = (bid & 63) * 2;
    const float* srcA = feat2 + ((size_t)(b*128 + c)) * HW;
    const float* srcB = srcA + HW;
    #pragma unroll
    for (int k = 0; k < 9; ++k) {
      int i = (k*1024 + t) * 4;
      f32x4 va = *(const f32x4*)(srcA + i);
      f32x4 vb = *(const f32x4*)(srcB + i);
      u32x4 pk;
      #pragma unroll
      for (int j = 0; j < 4; ++j)
        pk[j] = (uint32_t)f2bf(va[j]) | ((uint32_t)f2bf(vb[j]) << 16);
      *(u32x4*)&plane[i] = pk;
    }
    __syncthreads();
    int pbase = b*CW2;
    #pragma unroll
    for (int it = 0; it < 2; ++it) {
      int p = it*1024 + t;
      if (p < CW2) {
        int r = p / CROPW, cx = p % CROPW;
        int y = CROPOFF + r, x = CROPOFF + cx;
        float ax = aflow[((b*2 + 0)*Hh + y)*Ww + x];
        float ay = aflow[((b*2 + 1)*Hh + y)*Ww + x];
        // replicate reference's normalize->denormalize round trip
        float gxn = ax * (2.0f/(Ww-1)) - 1.0f;
        float gyn = ay * (2.0f/(Hh-1)) - 1.0f;
        float gx = (gxn + 1.0f) * 0.5f * (Ww-1);
        float gy = (gyn + 1.0f) * 0.5f * (Hh-1);
        // clamp base cell to 190: gx==191 shifts weight to the x=191 tap
        int xi = min((int)floorf(gx), Ww-2);
        int yi = min((int)floorf(gy), Hh-2);
        float wx1 = gx - (float)xi, wx0 = 1.f - wx1;
        float wy1 = gy - (float)yi, wy0 = 1.f - wy1;
        int cell = yi*Ww + xi;
        uint32_t u00 = plane[cell];
        uint32_t u01 = plane[cell + 1];
        uint32_t u10 = plane[cell + Ww];
        uint32_t u11 = plane[cell + Ww + 1];
        float v0 = wy0*(wx0*bf2f((ushort)u00) + wx1*bf2f((ushort)u01))
                 + wy1*(wx0*bf2f((ushort)u10) + wx1*bf2f((ushort)u11));
        float v1 = wy0*(wx0*bf2f((ushort)(u00>>16)) + wx1*bf2f((ushort)(u01>>16)))
                 + wy1*(wx0*bf2f((ushort)(u10>>16)) + wx1*bf2f((ushort)(u11>>16)));
        ushort q0 = f2bf(v0), q1 = f2bf(v1);
        *(uint32_t*)&pB[(size_t)(pbase + p)*128 + c] = (uint32_t)q0 | ((uint32_t)q1 << 16);
        float f0 = bf2f(q0), f1 = bf2f(q1);
        atomicAdd(&d2[pbase + p], f0*f0 + f1*f1);
      }
    }
  } else if (bid < SLABB + CROPB) {
    // ---------------- crop row: feat1 -> aB (channel-last bf16) + d1 ----------
    ushort* lsh = (ushort*)plane;       // 38*136 ushorts
    int rb2 = bid - SLABB;
    int b = rb2 / CROPW, r = rb2 % CROPW;
    int y = CROPOFF + r;
    {
      int xo = t & 63, cg = t >> 6;     // 38 active lanes; 16 groups x 8 ch
      if (xo < CROPW) {
        const float* src = feat1 + ((size_t)b*128*HW) + (size_t)y*Ww + CROPOFF + xo;
        #pragma unroll
        for (int k = 0; k < 8; ++k) {
          int cc = cg + k*16;
          lsh[xo*136 + cc] = f2bf(src[(size_t)cc*HW]);
        }
      }
    }
    __syncthreads();
    int chunk = t & 7, p = t >> 3;      // 128 p-slots, 38 active
    if (p < CROPW) {
      int idx = b*CW2 + r*CROPW + p;
      ushort* dst = aB + (size_t)idx*128 + chunk*16;
      *(bf16x8*)dst       = *(const bf16x8*)&lsh[p*136 + chunk*16];
      *(bf16x8*)(dst + 8) = *(const bf16x8*)&lsh[p*136 + chunk*16 + 8];
      float s = 0.f;
      #pragma unroll
      for (int j = 0; j < 16; ++j) {
        float v = bf2f(lsh[p*136 + chunk*16 + j]);
        s += v*v;
      }
      s += __shfl_xor(s, 1); s += __shfl_xor(s, 2); s += __shfl_xor(s, 4);
      if (chunk == 0) d1[idx] = s;
    }
  } else {
    // ---------------- pad rows: zero aB/pB, d1=0, d2=big ----------------
    if (t < NPAD - NPTS) {
      int row = NPTS + t;
      u32x4 z = {0,0,0,0};
      #pragma unroll
      for (int c = 0; c < 8; ++c) {
        *(u32x4*)&aB[(size_t)row*128 + c*16] = z;
        *(u32x4*)&aB[(size_t)row*128 + c*16 + 8] = z;
        *(u32x4*)&pB[(size_t)row*128 + c*16] = z;
        *(u32x4*)&pB[(size_t)row*128 + c*16 + 8] = z;
      }
      d1[row] = 0.f;
      d2[row] = 1e30f;
    }
  }
}

// ---- persistent fused GEMM: 32x32x16 MFMA, A in regs, B LDS double-buffer ----
// 256 thr, 4 waves (2x2), wave tile 64x64 (2x2 blocks of 32x32, 8 K-steps).
// Swapped MFMA (mfma(P, A)): C col = lane&31 = anchor row. C/D map:
// col=l&31, row=(reg&3)+8*(reg>>2)+4*(l>>5)  [HW-verified m74/m101].
// LDS swizzle (row&15)<<4 on BOTH stage-source and read -> 2-way max.
__global__ __launch_bounds__(256) void gemmp_k(
    const ushort* __restrict__ aB, const ushort* __restrict__ pB,
    const float* __restrict__ d1, const float* __restrict__ d2,
    float* __restrict__ pos, float* __restrict__ pmin) {
  __shared__ __align__(16) ushort lB[2][128*128];   // 2 x 32 KB

  // m204 bijective chunked XCD swizzle: nwg=460, q=57, r=4
  int bid = blockIdx.x;
  int xcd = bid & 7, kk = bid >> 3;
  int start = (xcd < 4) ? xcd*58 : 232 + (xcd-4)*57;
  int L = start + kk;
  int g = L / NMT, tM = L % NMT;
  int j0 = g * JPB;
  int jn = (NCT - j0 < JPB) ? (NCT - j0) : JPB;

  int tid = threadIdx.x;
  int rowg = tid >> 4, cb = (tid & 15) << 4;
  int w = tid >> 6, l = tid & 63;
  int wr = w >> 1, wc = w & 1;          // 2M x 2N waves; wave tile 64x64
  int l31 = l & 31, hi = l >> 5;
  int rsw = (l31 & 15) << 4;            // read-side XOR for row l31-based reads

  {  // stage B0 (swizzled source, linear dest): 128 rows x 256 B
    const char* gB = (const char*)pB + (size_t)j0 * 128 * 256;
    #pragma unroll
    for (int rnd = 0; rnd < 8; ++rnd) {
      int row = rnd*16 + rowg;
      g2l16(gB + row*256 + (cb ^ ((row&15)<<4)), (char*)lB[0] + row*256 + cb);
    }
  }

  // hoist A fragments once: row = tM*128 + wr*64 + mb*32 + l31, byte s*32+hi*16
  bf16x8 aF[16];                        // [mb*8+s], 64 VGPR
  {
    const char* gA = (const char*)aB + ((size_t)(tM*128 + wr*64 + l31))*256 + hi*16;
    #pragma unroll
    for (int mb = 0; mb < 2; ++mb)
      #pragma unroll
      for (int s = 0; s < 8; ++s)
        aF[mb*8+s] = *(const bf16x8*)(gA + mb*32*256 + s*32);
  }
  __syncthreads();   // drains vmcnt (B0 + aF)

  float mPart[2] = {BIGF, BIGF};

  for (int it = 0; it < jn; ++it) {
    int j = j0 + it;
    if (it + 1 < jn) {  // prefetch next B into alt buffer (overlaps compute)
      const char* gB = (const char*)pB + (size_t)(j+1) * 128 * 256;
      char* dst = (char*)lB[(it+1) & 1];
      #pragma unroll
      for (int rnd = 0; rnd < 8; ++rnd) {
        int row = rnd*16 + rowg;
        g2l16(gB + row*256 + (cb ^ ((row&15)<<4)), dst + row*256 + cb);
      }
    }
    // d2v early: latency hides under the MFMA loop below
    f32x4 d2v[2][4];
    #pragma unroll
    for (int nb = 0; nb < 2; ++nb)
      #pragma unroll
      for (int q = 0; q < 4; ++q)
        d2v[nb][q] = *(const f32x4*)&d2[j*128 + wc*64 + nb*32 + q*8 + hi*4];

    const char* bufB = (const char*)lB[it & 1];
    f32x16 acc[2][2] = {};              // acc[nb][mb]
    __builtin_amdgcn_s_setprio(1);
    #pragma unroll
    for (int s = 0; s < 8; ++s) {
      int cbase = s*32 + hi*16;
      bf16x8 pF[2];
      #pragma unroll
      for (int nb = 0; nb < 2; ++nb)
        pF[nb] = *(const bf16x8*)(bufB + (wc*64 + nb*32 + l31)*256 + (cbase ^ rsw));
      #pragma unroll
      for (int nb = 0; nb < 2; ++nb)
        #pragma unroll
        for (int mb = 0; mb < 2; ++mb)
          acc[nb][mb] = __builtin_amdgcn_mfma_f32_32x32x16_bf16(pF[nb], aF[mb*8+s], acc[nb][mb], 0, 0, 0);
    }
    __builtin_amdgcn_s_setprio(0);

    // epilogue in t-space: t = d2[col] - 2*dot; min accumulates in mPart regs
    if (j != tM) {                      // non-diagonal col-tile (uniform branch)
      #pragma unroll
      for (int mb = 0; mb < 2; ++mb)
        #pragma unroll
        for (int nb = 0; nb < 2; ++nb)
          #pragma unroll
          for (int reg = 0; reg < 16; ++reg)
            mPart[mb] = fminf(mPart[mb],
                fmaf(-2.f, acc[nb][mb][reg], d2v[nb][reg>>2][reg&3]));
    } else {                            // diagonal tile
      #pragma unroll
      for (int mb = 0; mb < 2; ++mb) {
        int gi = tM*128 + wr*64 + mb*32 + l31;
        #pragma unroll
        for (int nb = 0; nb < 2; ++nb)
          #pragma unroll
          for (int reg = 0; reg < 16; ++reg) {
            int gj = j*128 + wc*64 + nb*32 + (reg&3) + 8*(reg>>2) + 4*hi;
            float t = fmaf(-2.f, acc[nb][mb][reg], d2v[nb][reg>>2][reg&3]);
            if (gi == gj)
              pos[gi] = sqrtf(fmaxf(d1[gi] + t, 0.f) + 1e-6f) + 1e-8f;
            else
              mPart[mb] = fminf(mPart[mb], t);
          }
      }
    }
    __syncthreads();                    // next buffer staged + all reads done
  }

  // reduce: across half-wave (xor 32), then across wc waves via LDS scratch
  #pragma unroll
  for (int mb = 0; mb < 2; ++mb)
    mPart[mb] = fminf(mPart[mb], __shfl_xor(mPart[mb], 32));
  float* sm = (float*)lB;               // scratch [2][128]
  if (l < 32) {
    #pragma unroll
    for (int mb = 0; mb < 2; ++mb)
      sm[wc*128 + wr*64 + mb*32 + l] = mPart[mb];
  }
  __syncthreads();
  if (tid < 128) {
    int row = tM*128 + tid;
    float u = fminf(sm[tid], sm[128 + tid]);
    pmin[g*NPAD + row] = sqrtf(fmaxf(d1[row] + u, 0.f) + 1e-6f) + 1e-8f;
  }
}

// -------- finalize: min over group partials (+ diag+10 cand), mean relu --------
__global__ __launch_bounds__(1024) void fin_k(const float* __restrict__ pos,
                                              const float* __restrict__ pmin,
                                              float* __restrict__ out) {
  float s = 0.f;
  for (int i = threadIdx.x; i < NPTS; i += 1024) {
    float p = pos[i];
    float mneg = p + 10.f;              // diagonal's +10-modified candidate
    #pragma unroll
    for (int g = 0; g < NG; ++g) mneg = fminf(mneg, pmin[g*NPAD + i]);
    s += fmaxf(1.0f + p - mneg, 0.f);
  }
  for (int off = 1; off < 64; off <<= 1) s += __shfl_xor(s, off);
  __shared__ float red[16];
  if ((threadIdx.x & 63) == 0) red[threadIdx.x >> 6] = s;
  __syncthreads();
  if (threadIdx.x == 0) {
    float t = 0.f;
    #pragma unroll
    for (int k = 0; k < 16; ++k) t += red[k];
    out[0] = t / (float)NPTS;
  }
}

extern "C" void kernel_launch(void* const* d_in, const int* in_sizes, int n_in,
                              void* d_out, int out_size, void* d_ws, size_t ws_size,
                              hipStream_t stream) {
  const float* feat1 = (const float*)d_in[0];
  const float* feat2 = (const float*)d_in[1];
  const float* aflow = (const float*)d_in[2];

  char* ws = (char*)d_ws;
  ushort* aB = (ushort*)ws;                                   // NPAD*128 bf16
  ushort* pB = aB + (size_t)NPAD * 128;                       // NPAD*128 bf16
  float*  d1 = (float*)(pB + (size_t)NPAD * 128);             // NPAD f32
  float*  d2 = d1 + NPAD;
  float*  pos = d2 + NPAD;
  float*  pmin = pos + NPAD;                                  // NG*NPAD f32

  hipMemsetAsync(d2, 0, NPTS * sizeof(float), stream);        // slab atomics base
  hipLaunchKernelGGL(fused_k, dim3(SLABB + CROPB + 1), dim3(1024), 0, stream,
                     feat1, feat2, aflow, aB, pB, d1, d2);
  hipLaunchKernelGGL(gemmp_k, dim3(NBLK), dim3(256), 0, stream,
                     aB, pB, d1, d2, pos, pmin);
  hipLaunchKernelGGL(fin_k, dim3(1), dim3(1024), 0, stream,
                     pos, pmin, (float*)d_out);
}

// Round 11
// 115.906 us; speedup vs baseline: 1.0474x; 1.0474x over previous
//
#include <hip/hip_runtime.h>
#include <stdint.h>

#define Hh 192
#define Ww 192
#define HW 36864            // 192*192
#define CROPW 38
#define CW2 1444            // 38*38
#define CROPOFF 77
#define NPTS 11552          // 8*38*38
#define NPAD 11776          // 92*128
#define NMT 92              // 128-row tiles
#define NCT 92              // 128-col tiles
#define NG 5                // col-tile groups
#define JPB 19              // col-tiles per group (last group gets 16)
#define NBLK (NG*NMT)       // 460 blocks
#define SLABB 512           // 8 b * 64 channel-pairs
#define CROPB 304           // 38*8 crop blocks
#define BIGF 3.0e38f

typedef short bf16x8 __attribute__((ext_vector_type(8)));
typedef float f32x4 __attribute__((ext_vector_type(4)));
typedef uint32_t u32x4 __attribute__((ext_vector_type(4)));
typedef unsigned short ushort;

__device__ __forceinline__ ushort f2bf(float f) {
  uint32_t b = __float_as_uint(f);
  uint32_t r = b + 0x7fffu + ((b >> 16) & 1u);
  return (ushort)(r >> 16);
}
__device__ __forceinline__ float bf2f(ushort u) {
  return __uint_as_float(((uint32_t)u) << 16);
}

__device__ __forceinline__ void g2l16(const void* g, void* l) {
  __builtin_amdgcn_global_load_lds(
      (const __attribute__((address_space(1))) unsigned int*)g,
      (__attribute__((address_space(3))) unsigned int*)l, 16, 0, 0);
}

// ---- fused sampler: slab blocks (feat2->pB,hd2) + crop blocks (feat1->aB,d1) ----
// hd2 = 0.5 * ||p||^2 accumulated via atomicAdd (d2 zeroed by memset before).
__global__ __launch_bounds__(1024) void fused_k(
    const float* __restrict__ feat1, const float* __restrict__ feat2,
    const float* __restrict__ aflow,
    ushort* __restrict__ aB, ushort* __restrict__ pB,
    float* __restrict__ d1, float* __restrict__ d2,
    unsigned* __restrict__ cnt) {
  __shared__ __align__(16) uint32_t plane[HW];   // 144 KB (slab) / reused by crop
  int bid = blockIdx.x;
  int t = threadIdx.x;

  if (bid < SLABB) {
    // ---------------- slab: (b, channel-pair) ----------------
    int b = bid >> 6, c = (bid & 63) * 2;
    const float* srcA = feat2 + ((size_t)(b*128 + c)) * HW;
    const float* srcB = srcA + HW;
    #pragma unroll
    for (int k = 0; k < 9; ++k) {
      int i = (k*1024 + t) * 4;
      f32x4 va = *(const f32x4*)(srcA + i);
      f32x4 vb = *(const f32x4*)(srcB + i);
      u32x4 pk;
      #pragma unroll
      for (int j = 0; j < 4; ++j)
        pk[j] = (uint32_t)f2bf(va[j]) | ((uint32_t)f2bf(vb[j]) << 16);
      *(u32x4*)&plane[i] = pk;
    }
    __syncthreads();
    int pbase = b*CW2;
    #pragma unroll
    for (int it = 0; it < 2; ++it) {
      int p = it*1024 + t;
      if (p < CW2) {
        int r = p / CROPW, cx = p % CROPW;
        int y = CROPOFF + r, x = CROPOFF + cx;
        float ax = aflow[((b*2 + 0)*Hh + y)*Ww + x];
        float ay = aflow[((b*2 + 1)*Hh + y)*Ww + x];
        // replicate reference's normalize->denormalize round trip
        float gxn = ax * (2.0f/(Ww-1)) - 1.0f;
        float gyn = ay * (2.0f/(Hh-1)) - 1.0f;
        float gx = (gxn + 1.0f) * 0.5f * (Ww-1);
        float gy = (gyn + 1.0f) * 0.5f * (Hh-1);
        // clamp base cell to 190: gx==191 shifts weight to the x=191 tap
        int xi = min((int)floorf(gx), Ww-2);
        int yi = min((int)floorf(gy), Hh-2);
        float wx1 = gx - (float)xi, wx0 = 1.f - wx1;
        float wy1 = gy - (float)yi, wy0 = 1.f - wy1;
        int cell = yi*Ww + xi;
        uint32_t u00 = plane[cell];
        uint32_t u01 = plane[cell + 1];
        uint32_t u10 = plane[cell + Ww];
        uint32_t u11 = plane[cell + Ww + 1];
        float v0 = wy0*(wx0*bf2f((ushort)u00) + wx1*bf2f((ushort)u01))
                 + wy1*(wx0*bf2f((ushort)u10) + wx1*bf2f((ushort)u11));
        float v1 = wy0*(wx0*bf2f((ushort)(u00>>16)) + wx1*bf2f((ushort)(u01>>16)))
                 + wy1*(wx0*bf2f((ushort)(u10>>16)) + wx1*bf2f((ushort)(u11>>16)));
        ushort q0 = f2bf(v0), q1 = f2bf(v1);
        *(uint32_t*)&pB[(size_t)(pbase + p)*128 + c] = (uint32_t)q0 | ((uint32_t)q1 << 16);
        float f0 = bf2f(q0), f1 = bf2f(q1);
        atomicAdd(&d2[pbase + p], 0.5f*(f0*f0 + f1*f1));   // HALF norm
      }
    }
  } else if (bid < SLABB + CROPB) {
    // ---------------- crop row: feat1 -> aB (channel-last bf16) + d1 ----------
    ushort* lsh = (ushort*)plane;       // 38*136 ushorts
    int rb2 = bid - SLABB;
    int b = rb2 / CROPW, r = rb2 % CROPW;
    int y = CROPOFF + r;
    {
      int xo = t & 63, cg = t >> 6;     // 38 active lanes; 16 groups x 8 ch
      if (xo < CROPW) {
        const float* src = feat1 + ((size_t)b*128*HW) + (size_t)y*Ww + CROPOFF + xo;
        #pragma unroll
        for (int k = 0; k < 8; ++k) {
          int cc = cg + k*16;
          lsh[xo*136 + cc] = f2bf(src[(size_t)cc*HW]);
        }
      }
    }
    __syncthreads();
    int chunk = t & 7, p = t >> 3;      // 128 p-slots, 38 active
    if (p < CROPW) {
      int idx = b*CW2 + r*CROPW + p;
      ushort* dst = aB + (size_t)idx*128 + chunk*16;
      *(bf16x8*)dst       = *(const bf16x8*)&lsh[p*136 + chunk*16];
      *(bf16x8*)(dst + 8) = *(const bf16x8*)&lsh[p*136 + chunk*16 + 8];
      float s = 0.f;
      #pragma unroll
      for (int j = 0; j < 16; ++j) {
        float v = bf2f(lsh[p*136 + chunk*16 + j]);
        s += v*v;
      }
      s += __shfl_xor(s, 1); s += __shfl_xor(s, 2); s += __shfl_xor(s, 4);
      if (chunk == 0) d1[idx] = s;
    }
  } else {
    // ---------------- pad rows + counter zero ----------------
    if (t == 0) *cnt = 0;
    if (t < NPAD - NPTS) {
      int row = NPTS + t;
      u32x4 z = {0,0,0,0};
      #pragma unroll
      for (int c = 0; c < 8; ++c) {
        *(u32x4*)&aB[(size_t)row*128 + c*16] = z;
        *(u32x4*)&aB[(size_t)row*128 + c*16 + 8] = z;
        *(u32x4*)&pB[(size_t)row*128 + c*16] = z;
        *(u32x4*)&pB[(size_t)row*128 + c*16 + 8] = z;
      }
      d1[row] = 0.f;
      d2[row] = 5e29f;                  // half of 1e30 sentinel
    }
  }
}

// ---- persistent fused GEMM (R9-proven): A in regs, B LDS dbuf, 2 blocks/CU ----
// 256 thr, 4 waves (2x2), wave tile 64x64. Swapped MFMA: anchor in lane&15.
// Epilogue in half-t space: q = hd2[col] - dot; sq = d1 + 2q. 4 independent
// min chains + tree (min3-fusable). Last block (atomic counter) runs the
// final loss reduction (fin fold).
__global__ __launch_bounds__(256) void gemmp_k(
    const ushort* __restrict__ aB, const ushort* __restrict__ pB,
    const float* __restrict__ d1, const float* __restrict__ hd2,
    float* __restrict__ pos, float* __restrict__ pmin,
    unsigned* __restrict__ cnt, float* __restrict__ out) {
  __shared__ __align__(16) ushort lB[2][128*128];   // 2 x 32 KB
  __shared__ int lastf;

  // m204 bijective chunked XCD swizzle: nwg=460, q=57, r=4
  int bid = blockIdx.x;
  int xcd = bid & 7, kk = bid >> 3;
  int start = (xcd < 4) ? xcd*58 : 232 + (xcd-4)*57;
  int L = start + kk;
  int g = L / NMT, tM = L % NMT;
  int j0 = g * JPB;
  int jn = (NCT - j0 < JPB) ? (NCT - j0) : JPB;

  int tid = threadIdx.x;
  int rowg = tid >> 4, cb = (tid & 15) << 4;
  int w = tid >> 6, l = tid & 63;
  int wr = w >> 1, wc = w & 1;          // 2M x 2N waves; wave tile 64x64
  int lcol = l & 15, hq = l >> 4, rb = hq << 2;
  int rsw = (lcol & 7) << 4;

  {  // stage B0 (swizzled source, linear dest): 128 rows x 256 B
    const char* gB = (const char*)pB + (size_t)j0 * 128 * 256;
    #pragma unroll
    for (int rnd = 0; rnd < 8; ++rnd) {
      int row = rnd*16 + rowg;
      g2l16(gB + row*256 + (cb ^ ((row&7)<<4)), (char*)lB[0] + row*256 + cb);
    }
  }

  // hoist A fragments once: row = tM*128 + wr*64 + ma*16 + lcol
  bf16x8 aF[16];                        // [ma*4+ks], 64 VGPR
  {
    const char* gA = (const char*)aB + ((size_t)(tM*128 + wr*64 + lcol))*256 + hq*16;
    #pragma unroll
    for (int ma = 0; ma < 4; ++ma)
      #pragma unroll
      for (int ks = 0; ks < 4; ++ks)
        aF[ma*4+ks] = *(const bf16x8*)(gA + ma*16*256 + ks*64);
  }
  __syncthreads();   // drains vmcnt (B0 + aF)

  float mPart[4] = {BIGF, BIGF, BIGF, BIGF};   // running min of q per ma

  for (int it = 0; it < jn; ++it) {
    int j = j0 + it;
    if (it + 1 < jn) {  // prefetch next B into alt buffer (overlaps compute)
      const char* gB = (const char*)pB + (size_t)(j+1) * 128 * 256;
      char* dst = (char*)lB[(it+1) & 1];
      #pragma unroll
      for (int rnd = 0; rnd < 8; ++rnd) {
        int row = rnd*16 + rowg;
        g2l16(gB + row*256 + (cb ^ ((row&7)<<4)), dst + row*256 + cb);
      }
    }
    // hd2 early: latency hides under the MFMA loop below
    f32x4 d2v[4];
    #pragma unroll
    for (int np = 0; np < 4; ++np)
      d2v[np] = *(const f32x4*)&hd2[j*128 + wc*64 + np*16 + rb];

    const char* bufB = (const char*)lB[it & 1];
    f32x4 acc[4][4] = {};               // acc[np][ma]
    #pragma unroll
    for (int ks = 0; ks < 4; ++ks) {
      int cbase = ks*64 + (hq << 4);
      bf16x8 bF[4];
      #pragma unroll
      for (int np = 0; np < 4; ++np)
        bF[np] = *(const bf16x8*)(bufB + (wc*64 + np*16 + lcol)*256 + (cbase ^ rsw));
      #pragma unroll
      for (int np = 0; np < 4; ++np)
        #pragma unroll
        for (int ma = 0; ma < 4; ++ma)
          acc[np][ma] = __builtin_amdgcn_mfma_f32_16x16x32_bf16(bF[np], aF[ma*4+ks], acc[np][ma], 0, 0, 0);
    }

    // epilogue: q = hd2[col] - dot; 4 independent chains + tree combine
    if (j != tM) {                      // non-diagonal col-tile (uniform branch)
      #pragma unroll
      for (int ma = 0; ma < 4; ++ma) {
        float v0 = BIGF, v1 = BIGF, v2 = BIGF, v3 = BIGF;
        #pragma unroll
        for (int np = 0; np < 4; ++np) {
          v0 = fminf(v0, d2v[np][0] - acc[np][ma][0]);
          v1 = fminf(v1, d2v[np][1] - acc[np][ma][1]);
          v2 = fminf(v2, d2v[np][2] - acc[np][ma][2]);
          v3 = fminf(v3, d2v[np][3] - acc[np][ma][3]);
        }
        mPart[ma] = fminf(mPart[ma], fminf(fminf(v0, v1), fminf(v2, v3)));
      }
    } else {                            // diagonal tile (once per block)
      #pragma unroll
      for (int ma = 0; ma < 4; ++ma) {
        int gi = tM*128 + wr*64 + ma*16 + lcol;
        #pragma unroll
        for (int np = 0; np < 4; ++np)
          #pragma unroll
          for (int reg = 0; reg < 4; ++reg) {
            int gj = j*128 + wc*64 + np*16 + rb + reg;
            float q = d2v[np][reg] - acc[np][ma][reg];
            if (gi == gj) {
              pos[gi] = sqrtf(fmaxf(d1[gi] + 2.f*q, 0.f) + 1e-6f) + 1e-8f;
              q = BIGF;
            }
            mPart[ma] = fminf(mPart[ma], q);
          }
      }
    }
    __syncthreads();                    // next buffer staged + all reads done
  }

  // final reduce: over hq via shuffles, over wc via LDS scratch; non-atomic store
  #pragma unroll
  for (int ma = 0; ma < 4; ++ma) {
    float u = mPart[ma];
    u = fminf(u, __shfl_xor(u, 16));
    u = fminf(u, __shfl_xor(u, 32));
    mPart[ma] = u;
  }
  __syncthreads();
  float* sm = (float*)lB;               // scratch [2][128]
  if (hq == 0) {
    #pragma unroll
    for (int ma = 0; ma < 4; ++ma)
      sm[wc*128 + wr*64 + ma*16 + lcol] = mPart[ma];
  }
  __syncthreads();
  if (tid < 128) {
    int row = tM*128 + tid;
    float u = fminf(sm[tid], sm[128 + tid]);
    pmin[g*NPAD + row] = sqrtf(fmaxf(d1[row] + 2.f*u, 0.f) + 1e-6f) + 1e-8f;
  }

  // ---- last-block loss reduction (fin fold) ----
  __threadfence();                      // release pmin/pos stores
  __syncthreads();
  if (tid == 0) {
    unsigned old = atomicAdd(cnt, 1u);
    lastf = (old == NBLK - 1u);
  }
  __syncthreads();
  if (lastf) {
    __threadfence();                    // acquire other blocks' stores
    float s = 0.f;
    for (int i = tid*4; i < NPTS; i += 1024) {
      f32x4 p = *(const f32x4*)&pos[i];
      f32x4 mn;
      #pragma unroll
      for (int jj = 0; jj < 4; ++jj) mn[jj] = p[jj] + 10.f;
      #pragma unroll
      for (int gg = 0; gg < NG; ++gg) {
        f32x4 pm = *(const f32x4*)&pmin[gg*NPAD + i];
        #pragma unroll
        for (int jj = 0; jj < 4; ++jj) mn[jj] = fminf(mn[jj], pm[jj]);
      }
      #pragma unroll
      for (int jj = 0; jj < 4; ++jj)
        s += fmaxf(1.0f + p[jj] - mn[jj], 0.f);
    }
    for (int off = 1; off < 64; off <<= 1) s += __shfl_xor(s, off);
    __syncthreads();
    if (l == 0) sm[w] = s;
    __syncthreads();
    if (tid == 0)
      out[0] = (sm[0] + sm[1] + sm[2] + sm[3]) / (float)NPTS;
  }
}

extern "C" void kernel_launch(void* const* d_in, const int* in_sizes, int n_in,
                              void* d_out, int out_size, void* d_ws, size_t ws_size,
                              hipStream_t stream) {
  const float* feat1 = (const float*)d_in[0];
  const float* feat2 = (const float*)d_in[1];
  const float* aflow = (const float*)d_in[2];

  char* ws = (char*)d_ws;
  ushort* aB = (ushort*)ws;                                   // NPAD*128 bf16
  ushort* pB = aB + (size_t)NPAD * 128;                       // NPAD*128 bf16
  float*  d1 = (float*)(pB + (size_t)NPAD * 128);             // NPAD f32
  float*  d2 = d1 + NPAD;                                     // HALF norms
  float*  pos = d2 + NPAD;
  float*  pmin = pos + NPAD;                                  // NG*NPAD f32
  unsigned* cnt = (unsigned*)(pmin + (size_t)NG*NPAD);

  hipMemsetAsync(d2, 0, NPTS * sizeof(float), stream);        // slab atomics base
  hipLaunchKernelGGL(fused_k, dim3(SLABB + CROPB + 1), dim3(1024), 0, stream,
                     feat1, feat2, aflow, aB, pB, d1, d2, cnt);
  hipLaunchKernelGGL(gemmp_k, dim3(NBLK), dim3(256), 0, stream,
                     aB, pB, d1, d2, pos, pmin, cnt, (float*)d_out);
}

// Round 12
// 88.789 us; speedup vs baseline: 1.3673x; 1.3054x over previous
//
#include <hip/hip_runtime.h>
#include <stdint.h>

#define Hh 192
#define Ww 192
#define HW 36864            // 192*192
#define CROPW 38
#define CW2 1444            // 38*38
#define CROPOFF 77
#define NPTS 11552          // 8*38*38
#define NPAD 11776          // 92*128
#define NMT 92              // 128-row tiles
#define NCT 92              // 128-col tiles
#define NG 5                // col-tile groups
#define JPB 19              // col-tiles per group (last group gets 16)
#define NBLK (NG*NMT)       // 460 blocks
#define SLABB 512           // 8 b * 64 channel-pairs
#define CROPB 304           // 38*8 crop blocks
#define BIGF 3.0e38f

typedef short bf16x8 __attribute__((ext_vector_type(8)));
typedef float f32x4 __attribute__((ext_vector_type(4)));
typedef uint32_t u32x4 __attribute__((ext_vector_type(4)));
typedef unsigned short ushort;

__device__ __forceinline__ ushort f2bf(float f) {
  uint32_t b = __float_as_uint(f);
  uint32_t r = b + 0x7fffu + ((b >> 16) & 1u);
  return (ushort)(r >> 16);
}
__device__ __forceinline__ float bf2f(ushort u) {
  return __uint_as_float(((uint32_t)u) << 16);
}

__device__ __forceinline__ void g2l16(const void* g, void* l) {
  __builtin_amdgcn_global_load_lds(
      (const __attribute__((address_space(1))) unsigned int*)g,
      (__attribute__((address_space(3))) unsigned int*)l, 16, 0, 0);
}

// ---- fused sampler: slab blocks (feat2->pB,d2) + crop blocks (feat1->aB,d1) ----
// (R9-proven, unchanged)
__global__ __launch_bounds__(1024) void fused_k(
    const float* __restrict__ feat1, const float* __restrict__ feat2,
    const float* __restrict__ aflow,
    ushort* __restrict__ aB, ushort* __restrict__ pB,
    float* __restrict__ d1, float* __restrict__ d2) {
  __shared__ __align__(16) uint32_t plane[HW];   // 144 KB (slab) / reused by crop
  int bid = blockIdx.x;
  int t = threadIdx.x;

  if (bid < SLABB) {
    // ---------------- slab: (b, channel-pair) ----------------
    int b = bid >> 6, c = (bid & 63) * 2;
    const float* srcA = feat2 + ((size_t)(b*128 + c)) * HW;
    const float* srcB = srcA + HW;
    #pragma unroll
    for (int k = 0; k < 9; ++k) {
      int i = (k*1024 + t) * 4;
      f32x4 va = *(const f32x4*)(srcA + i);
      f32x4 vb = *(const f32x4*)(srcB + i);
      u32x4 pk;
      #pragma unroll
      for (int j = 0; j < 4; ++j)
        pk[j] = (uint32_t)f2bf(va[j]) | ((uint32_t)f2bf(vb[j]) << 16);
      *(u32x4*)&plane[i] = pk;
    }
    __syncthreads();
    int pbase = b*CW2;
    #pragma unroll
    for (int it = 0; it < 2; ++it) {
      int p = it*1024 + t;
      if (p < CW2) {
        int r = p / CROPW, cx = p % CROPW;
        int y = CROPOFF + r, x = CROPOFF + cx;
        float ax = aflow[((b*2 + 0)*Hh + y)*Ww + x];
        float ay = aflow[((b*2 + 1)*Hh + y)*Ww + x];
        // replicate reference's normalize->denormalize round trip
        float gxn = ax * (2.0f/(Ww-1)) - 1.0f;
        float gyn = ay * (2.0f/(Hh-1)) - 1.0f;
        float gx = (gxn + 1.0f) * 0.5f * (Ww-1);
        float gy = (gyn + 1.0f) * 0.5f * (Hh-1);
        // clamp base cell to 190: gx==191 shifts weight to the x=191 tap
        int xi = min((int)floorf(gx), Ww-2);
        int yi = min((int)floorf(gy), Hh-2);
        float wx1 = gx - (float)xi, wx0 = 1.f - wx1;
        float wy1 = gy - (float)yi, wy0 = 1.f - wy1;
        int cell = yi*Ww + xi;
        uint32_t u00 = plane[cell];
        uint32_t u01 = plane[cell + 1];
        uint32_t u10 = plane[cell + Ww];
        uint32_t u11 = plane[cell + Ww + 1];
        float v0 = wy0*(wx0*bf2f((ushort)u00) + wx1*bf2f((ushort)u01))
                 + wy1*(wx0*bf2f((ushort)u10) + wx1*bf2f((ushort)u11));
        float v1 = wy0*(wx0*bf2f((ushort)(u00>>16)) + wx1*bf2f((ushort)(u01>>16)))
                 + wy1*(wx0*bf2f((ushort)(u10>>16)) + wx1*bf2f((ushort)(u11>>16)));
        ushort q0 = f2bf(v0), q1 = f2bf(v1);
        *(uint32_t*)&pB[(size_t)(pbase + p)*128 + c] = (uint32_t)q0 | ((uint32_t)q1 << 16);
        float f0 = bf2f(q0), f1 = bf2f(q1);
        atomicAdd(&d2[pbase + p], f0*f0 + f1*f1);
      }
    }
  } else if (bid < SLABB + CROPB) {
    // ---------------- crop row: feat1 -> aB (channel-last bf16) + d1 ----------
    ushort* lsh = (ushort*)plane;       // 38*136 ushorts
    int rb2 = bid - SLABB;
    int b = rb2 / CROPW, r = rb2 % CROPW;
    int y = CROPOFF + r;
    {
      int xo = t & 63, cg = t >> 6;     // 38 active lanes; 16 groups x 8 ch
      if (xo < CROPW) {
        const float* src = feat1 + ((size_t)b*128*HW) + (size_t)y*Ww + CROPOFF + xo;
        #pragma unroll
        for (int k = 0; k < 8; ++k) {
          int cc = cg + k*16;
          lsh[xo*136 + cc] = f2bf(src[(size_t)cc*HW]);
        }
      }
    }
    __syncthreads();
    int chunk = t & 7, p = t >> 3;      // 128 p-slots, 38 active
    if (p < CROPW) {
      int idx = b*CW2 + r*CROPW + p;
      ushort* dst = aB + (size_t)idx*128 + chunk*16;
      *(bf16x8*)dst       = *(const bf16x8*)&lsh[p*136 + chunk*16];
      *(bf16x8*)(dst + 8) = *(const bf16x8*)&lsh[p*136 + chunk*16 + 8];
      float s = 0.f;
      #pragma unroll
      for (int j = 0; j < 16; ++j) {
        float v = bf2f(lsh[p*136 + chunk*16 + j]);
        s += v*v;
      }
      s += __shfl_xor(s, 1); s += __shfl_xor(s, 2); s += __shfl_xor(s, 4);
      if (chunk == 0) d1[idx] = s;
    }
  } else {
    // ---------------- pad rows: zero aB/pB, d1=0, d2=big ----------------
    if (t < NPAD - NPTS) {
      int row = NPTS + t;
      u32x4 z = {0,0,0,0};
      #pragma unroll
      for (int c = 0; c < 8; ++c) {
        *(u32x4*)&aB[(size_t)row*128 + c*16] = z;
        *(u32x4*)&aB[(size_t)row*128 + c*16 + 8] = z;
        *(u32x4*)&pB[(size_t)row*128 + c*16] = z;
        *(u32x4*)&pB[(size_t)row*128 + c*16 + 8] = z;
      }
      d1[row] = 0.f;
      d2[row] = 1e30f;
    }
  }
}

// ---- persistent fused GEMM: A in regs, B LDS dbuf, wave tile 128M x 32N ------
// 256 thr, 4 waves as 1M x 4N strips of the 128x128 block tile. B-fragment
// LDS reads halve vs 64x64 (ma-reuse 8): 8 b128/wave-iter. A hoisted once
// (128 VGPR). Swapped MFMA: anchor index in lane&15. R9 swizzle (row&7)<<4
// both-sides; no setprio; separate fin_k (R9-proven epilogue structure).
__global__ __launch_bounds__(256, 2) void gemmp_k(
    const ushort* __restrict__ aB, const ushort* __restrict__ pB,
    const float* __restrict__ d1, const float* __restrict__ d2,
    float* __restrict__ pos, float* __restrict__ pmin) {
  __shared__ __align__(16) ushort lB[2][128*128];   // 2 x 32 KB

  // m204 bijective chunked XCD swizzle: nwg=460, q=57, r=4
  int bid = blockIdx.x;
  int xcd = bid & 7, kk = bid >> 3;
  int start = (xcd < 4) ? xcd*58 : 232 + (xcd-4)*57;
  int L = start + kk;
  int g = L / NMT, tM = L % NMT;
  int j0 = g * JPB;
  int jn = (NCT - j0 < JPB) ? (NCT - j0) : JPB;

  int tid = threadIdx.x;
  int rowg = tid >> 4, cb = (tid & 15) << 4;
  int w = tid >> 6, l = tid & 63;
  int wc = w;                           // 4 N-strips of 32 cols; all waves share M=128
  int lcol = l & 15, hq = l >> 4, rb = hq << 2;
  int rsw = (lcol & 7) << 4;

  {  // stage B0 (swizzled source, linear dest): 128 rows x 256 B
    const char* gB = (const char*)pB + (size_t)j0 * 128 * 256;
    #pragma unroll
    for (int rnd = 0; rnd < 8; ++rnd) {
      int row = rnd*16 + rowg;
      g2l16(gB + row*256 + (cb ^ ((row&7)<<4)), (char*)lB[0] + row*256 + cb);
    }
  }

  // hoist A fragments once: row = tM*128 + ma*16 + lcol (ma=0..7), all waves same
  bf16x8 aF[32];                        // [ma*4+ks], 128 VGPR
  {
    const char* gA = (const char*)aB + ((size_t)(tM*128 + lcol))*256 + hq*16;
    #pragma unroll
    for (int ma = 0; ma < 8; ++ma)
      #pragma unroll
      for (int ks = 0; ks < 4; ++ks)
        aF[ma*4+ks] = *(const bf16x8*)(gA + ma*16*256 + ks*64);
  }
  __syncthreads();   // drains vmcnt (B0 + aF)

  float mPart[8] = {BIGF,BIGF,BIGF,BIGF,BIGF,BIGF,BIGF,BIGF};

  for (int it = 0; it < jn; ++it) {
    int j = j0 + it;
    if (it + 1 < jn) {  // prefetch next B into alt buffer (overlaps compute)
      const char* gB = (const char*)pB + (size_t)(j+1) * 128 * 256;
      char* dst = (char*)lB[(it+1) & 1];
      #pragma unroll
      for (int rnd = 0; rnd < 8; ++rnd) {
        int row = rnd*16 + rowg;
        g2l16(gB + row*256 + (cb ^ ((row&7)<<4)), dst + row*256 + cb);
      }
    }
    // d2v early: latency hides under the MFMA loop below
    f32x4 d2v[2];
    #pragma unroll
    for (int np = 0; np < 2; ++np)
      d2v[np] = *(const f32x4*)&d2[j*128 + wc*32 + np*16 + rb];

    const char* bufB = (const char*)lB[it & 1];
    f32x4 acc[2][8] = {};               // acc[np][ma]
    #pragma unroll
    for (int ks = 0; ks < 4; ++ks) {
      int cbase = ks*64 + (hq << 4);
      bf16x8 bF[2];
      #pragma unroll
      for (int np = 0; np < 2; ++np)
        bF[np] = *(const bf16x8*)(bufB + (wc*32 + np*16 + lcol)*256 + (cbase ^ rsw));
      #pragma unroll
      for (int np = 0; np < 2; ++np)
        #pragma unroll
        for (int ma = 0; ma < 8; ++ma)
          acc[np][ma] = __builtin_amdgcn_mfma_f32_16x16x32_bf16(bF[np], aF[ma*4+ks], acc[np][ma], 0, 0, 0);
    }

    // epilogue in t-space: t = d2[col] - 2*dot; min accumulates in mPart regs
    if (j != tM) {                      // non-diagonal col-tile (uniform branch)
      #pragma unroll
      for (int ma = 0; ma < 8; ++ma)
        #pragma unroll
        for (int np = 0; np < 2; ++np)
          #pragma unroll
          for (int reg = 0; reg < 4; ++reg)
            mPart[ma] = fminf(mPart[ma], fmaf(-2.f, acc[np][ma][reg], d2v[np][reg]));
    } else {                            // diagonal tile (once per block)
      #pragma unroll
      for (int ma = 0; ma < 8; ++ma) {
        int gi = tM*128 + ma*16 + lcol;
        #pragma unroll
        for (int np = 0; np < 2; ++np)
          #pragma unroll
          for (int reg = 0; reg < 4; ++reg) {
            int gj = j*128 + wc*32 + np*16 + rb + reg;
            float t = fmaf(-2.f, acc[np][ma][reg], d2v[np][reg]);
            if (gi == gj)
              pos[gi] = sqrtf(fmaxf(d1[gi] + t, 0.f) + 1e-6f) + 1e-8f;
            else
              mPart[ma] = fminf(mPart[ma], t);
          }
      }
    }
    __syncthreads();                    // next buffer staged + all reads done
  }

  // final reduce: over hq via shuffles, over the 4 col-strip waves via LDS
  #pragma unroll
  for (int ma = 0; ma < 8; ++ma) {
    float u = mPart[ma];
    u = fminf(u, __shfl_xor(u, 16));
    u = fminf(u, __shfl_xor(u, 32));
    mPart[ma] = u;
  }
  __syncthreads();
  float* sm = (float*)lB;               // scratch [4][128]
  if (hq == 0) {
    #pragma unroll
    for (int ma = 0; ma < 8; ++ma)
      sm[wc*128 + ma*16 + lcol] = mPart[ma];
  }
  __syncthreads();
  if (tid < 128) {
    int row = tM*128 + tid;
    float u = fminf(fminf(sm[tid], sm[128 + tid]),
                    fminf(sm[256 + tid], sm[384 + tid]));
    pmin[g*NPAD + row] = sqrtf(fmaxf(d1[row] + u, 0.f) + 1e-6f) + 1e-8f;
  }
}

// -------- finalize: min over group partials (+ diag+10 cand), mean relu --------
__global__ __launch_bounds__(1024) void fin_k(const float* __restrict__ pos,
                                              const float* __restrict__ pmin,
                                              float* __restrict__ out) {
  float s = 0.f;
  for (int i = threadIdx.x*4; i < NPTS; i += 4096) {
    f32x4 p = *(const f32x4*)&pos[i];
    f32x4 mn;
    #pragma unroll
    for (int jj = 0; jj < 4; ++jj) mn[jj] = p[jj] + 10.f;
    #pragma unroll
    for (int gg = 0; gg < NG; ++gg) {
      f32x4 pm = *(const f32x4*)&pmin[gg*NPAD + i];
      #pragma unroll
      for (int jj = 0; jj < 4; ++jj) mn[jj] = fminf(mn[jj], pm[jj]);
    }
    #pragma unroll
    for (int jj = 0; jj < 4; ++jj)
      s += fmaxf(1.0f + p[jj] - mn[jj], 0.f);
  }
  for (int off = 1; off < 64; off <<= 1) s += __shfl_xor(s, off);
  __shared__ float red[16];
  if ((threadIdx.x & 63) == 0) red[threadIdx.x >> 6] = s;
  __syncthreads();
  if (threadIdx.x == 0) {
    float t = 0.f;
    #pragma unroll
    for (int k = 0; k < 16; ++k) t += red[k];
    out[0] = t / (float)NPTS;
  }
}

extern "C" void kernel_launch(void* const* d_in, const int* in_sizes, int n_in,
                              void* d_out, int out_size, void* d_ws, size_t ws_size,
                              hipStream_t stream) {
  const float* feat1 = (const float*)d_in[0];
  const float* feat2 = (const float*)d_in[1];
  const float* aflow = (const float*)d_in[2];

  char* ws = (char*)d_ws;
  ushort* aB = (ushort*)ws;                                   // NPAD*128 bf16
  ushort* pB = aB + (size_t)NPAD * 128;                       // NPAD*128 bf16
  float*  d1 = (float*)(pB + (size_t)NPAD * 128);             // NPAD f32
  float*  d2 = d1 + NPAD;
  float*  pos = d2 + NPAD;
  float*  pmin = pos + NPAD;                                  // NG*NPAD f32

  hipMemsetAsync(d2, 0, NPTS * sizeof(float), stream);        // slab atomics base
  hipLaunchKernelGGL(fused_k, dim3(SLABB + CROPB + 1), dim3(1024), 0, stream,
                     feat1, feat2, aflow, aB, pB, d1, d2);
  hipLaunchKernelGGL(gemmp_k, dim3(NBLK), dim3(256), 0, stream,
                     aB, pB, d1, d2, pos, pmin);
  hipLaunchKernelGGL(fin_k, dim3(1), dim3(1024), 0, stream,
                     pos, pmin, (float*)d_out);
}